// Round 1
// baseline (116.972 us; speedup 1.0000x reference)
//
#include <hip/hip_runtime.h>
#include <math.h>

constexpr int Bb = 4, Cc = 64, Hh = 256, Ww = 256;

// Grid: B*H blocks, block (64,4). Each block computes one output row (b,h).
// threadIdx.x = 4-pixel group along W, threadIdx.y = channel group (16 ch each).
__global__ __launch_bounds__(256) void entropy_kernel(const float* __restrict__ x,
                                                      float* __restrict__ e) {
  const int b = blockIdx.x / Hh;
  const int h = blockIdx.x % Hh;
  const int tx = threadIdx.x;   // 0..63
  const int ty = threadIdx.y;   // 0..3
  const int w0 = tx * 4;

  float acc[4] = {0.f, 0.f, 0.f, 0.f};

  const size_t planeStride = (size_t)Hh * Ww;
  const float* xb = x + ((size_t)b * Cc + (size_t)ty * 16) * planeStride;

  for (int cc = 0; cc < 16; ++cc) {
    const float* plane = xb + (size_t)cc * planeStride;
    float va[3][4];
    float lft[3], rgt[3];
#pragma unroll
    for (int r = 0; r < 3; ++r) {
      const int hh2 = h + r - 1;
      float4 v;
      if (hh2 >= 0 && hh2 < Hh) {
        v = *reinterpret_cast<const float4*>(plane + (size_t)hh2 * Ww + w0);
      } else {
        v = make_float4(0.f, 0.f, 0.f, 0.f);
      }
      va[r][0] = v.x; va[r][1] = v.y; va[r][2] = v.z; va[r][3] = v.w;
      float l  = __shfl_up(v.w, 1, 64);
      float rr = __shfl_down(v.x, 1, 64);
      lft[r] = (tx == 0)  ? 0.f : l;
      rgt[r] = (tx == 63) ? 0.f : rr;
    }
#pragma unroll
    for (int i = 0; i < 4; ++i) {
      float vv[9];
#pragma unroll
      for (int r = 0; r < 3; ++r) {
        vv[r * 3 + 0] = (i == 0) ? lft[r] : va[r][i - 1];
        vv[r * 3 + 1] = va[r][i];
        vv[r * 3 + 2] = (i == 3) ? rgt[r] : va[r][i + 1];
      }
      float m = vv[0];
#pragma unroll
      for (int k = 1; k < 9; ++k) m = fmaxf(m, vv[k]);
      float s = 0.f, ws = 0.f;
#pragma unroll
      for (int k = 0; k < 9; ++k) {
        float d = vv[k] - m;
        float t = __expf(d);
        s += t;
        ws += t * d;
      }
      acc[i] += __logf(s) - ws * __builtin_amdgcn_rcpf(s);
    }
  }

  // Reduce the 4 channel groups.
  __shared__ float red[4][4][64];
#pragma unroll
  for (int i = 0; i < 4; ++i) red[ty][i][tx] = acc[i];
  __syncthreads();
  if (ty == 0) {
    float4 o;
    float* op = &o.x;
#pragma unroll
    for (int i = 0; i < 4; ++i) {
      op[i] = (red[0][i][tx] + red[1][i][tx] + red[2][i][tx] + red[3][i][tx]) *
              (1.0f / Cc);
    }
    *reinterpret_cast<float4*>(e + (size_t)blockIdx.x * Ww + w0) = o;
  }
}

// Grid: B blocks of 256 threads. Per-batch min/max over H*W floats.
__global__ __launch_bounds__(256) void minmax_kernel(const float* __restrict__ e,
                                                     float* __restrict__ stats) {
  const int b = blockIdx.x;
  const float* p = e + (size_t)b * Hh * Ww;
  float mn = INFINITY, mx = -INFINITY;
  for (int i = threadIdx.x; i < Hh * Ww; i += 256) {
    float v = p[i];
    mn = fminf(mn, v);
    mx = fmaxf(mx, v);
  }
#pragma unroll
  for (int off = 32; off > 0; off >>= 1) {
    mn = fminf(mn, __shfl_down(mn, off, 64));
    mx = fmaxf(mx, __shfl_down(mx, off, 64));
  }
  __shared__ float smn[4], smx[4];
  const int wave = threadIdx.x >> 6;
  if ((threadIdx.x & 63) == 0) { smn[wave] = mn; smx[wave] = mx; }
  __syncthreads();
  if (threadIdx.x == 0) {
    mn = fminf(fminf(smn[0], smn[1]), fminf(smn[2], smn[3]));
    mx = fmaxf(fmaxf(smx[0], smx[1]), fmaxf(smx[2], smx[3]));
    float denom = fmaxf(mx - mn, 1e-6f);
    stats[b * 2 + 0] = mn;
    stats[b * 2 + 1] = 1.0f / denom;
  }
}

// In-place normalize d_out. 65536 threads, 4 elements each (float4).
__global__ __launch_bounds__(256) void norm_kernel(float* __restrict__ e,
                                                   const float* __restrict__ stats) {
  const int t = blockIdx.x * 256 + threadIdx.x;           // 0..65535
  const int b = t >> 14;                                  // (t*4) >> 16
  const float mn  = stats[b * 2 + 0];
  const float inv = stats[b * 2 + 1];
  float4 v = reinterpret_cast<float4*>(e)[t];
  v.x = (v.x - mn) * inv;
  v.y = (v.y - mn) * inv;
  v.z = (v.z - mn) * inv;
  v.w = (v.w - mn) * inv;
  reinterpret_cast<float4*>(e)[t] = v;
}

extern "C" void kernel_launch(void* const* d_in, const int* in_sizes, int n_in,
                              void* d_out, int out_size, void* d_ws, size_t ws_size,
                              hipStream_t stream) {
  const float* x = (const float*)d_in[0];
  float* out = (float*)d_out;      // e, then normalized in place
  float* stats = (float*)d_ws;     // 8 floats: per-batch (min, 1/denom)

  entropy_kernel<<<dim3(Bb * Hh), dim3(64, 4), 0, stream>>>(x, out);
  minmax_kernel<<<dim3(Bb), dim3(256), 0, stream>>>(out, stats);
  norm_kernel<<<dim3((Bb * Hh * Ww / 4) / 256), dim3(256), 0, stream>>>(out, stats);
}

// Round 2
// 63.735 us; speedup vs baseline: 1.8353x; 1.8353x over previous
//
#include <hip/hip_runtime.h>
#include <math.h>

constexpr int Bb = 4, Cc = 64, Hh = 256, Ww = 256;

__device__ __forceinline__ unsigned int fenc(float f) {
  unsigned int u = __float_as_uint(f);
  return (u & 0x80000000u) ? ~u : (u | 0x80000000u);
}
__device__ __forceinline__ float fdec(unsigned int k) {
  return __uint_as_float((k & 0x80000000u) ? (k ^ 0x80000000u) : ~k);
}

// Grid: B*H blocks, block (64,4). Each block computes one output row (b,h),
// then contributes the row's min/max to per-batch atomics in stats.
// stats layout (uint): [0..3] = min keys per batch, [4..7] = max keys.
__global__ __launch_bounds__(256) void entropy_kernel(const float* __restrict__ x,
                                                      float* __restrict__ e,
                                                      unsigned int* __restrict__ stats) {
  const int b = blockIdx.x / Hh;
  const int h = blockIdx.x % Hh;
  const int tx = threadIdx.x;   // 0..63
  const int ty = threadIdx.y;   // 0..3
  const int w0 = tx * 4;

  float acc[4] = {0.f, 0.f, 0.f, 0.f};

  const size_t planeStride = (size_t)Hh * Ww;
  const float* xb = x + ((size_t)b * Cc + (size_t)ty * 16) * planeStride;

  for (int cc = 0; cc < 16; ++cc) {
    const float* plane = xb + (size_t)cc * planeStride;
    float va[3][4];
    float lft[3], rgt[3];
#pragma unroll
    for (int r = 0; r < 3; ++r) {
      const int hh2 = h + r - 1;
      float4 v;
      if (hh2 >= 0 && hh2 < Hh) {
        v = *reinterpret_cast<const float4*>(plane + (size_t)hh2 * Ww + w0);
      } else {
        v = make_float4(0.f, 0.f, 0.f, 0.f);
      }
      va[r][0] = v.x; va[r][1] = v.y; va[r][2] = v.z; va[r][3] = v.w;
      float l  = __shfl_up(v.w, 1, 64);
      float rr = __shfl_down(v.x, 1, 64);
      lft[r] = (tx == 0)  ? 0.f : l;
      rgt[r] = (tx == 63) ? 0.f : rr;
    }
#pragma unroll
    for (int i = 0; i < 4; ++i) {
      float vv[9];
#pragma unroll
      for (int r = 0; r < 3; ++r) {
        vv[r * 3 + 0] = (i == 0) ? lft[r] : va[r][i - 1];
        vv[r * 3 + 1] = va[r][i];
        vv[r * 3 + 2] = (i == 3) ? rgt[r] : va[r][i + 1];
      }
      float m = vv[0];
#pragma unroll
      for (int k = 1; k < 9; ++k) m = fmaxf(m, vv[k]);
      float s = 0.f, ws = 0.f;
#pragma unroll
      for (int k = 0; k < 9; ++k) {
        float d = vv[k] - m;
        float t = __expf(d);
        s += t;
        ws += t * d;
      }
      acc[i] += __logf(s) - ws * __builtin_amdgcn_rcpf(s);
    }
  }

  // Reduce the 4 channel groups.
  __shared__ float red[4][4][64];
#pragma unroll
  for (int i = 0; i < 4; ++i) red[ty][i][tx] = acc[i];
  __syncthreads();
  if (ty == 0) {
    float4 o;
    float* op = &o.x;
    float mn = INFINITY, mx = -INFINITY;
#pragma unroll
    for (int i = 0; i < 4; ++i) {
      float v = (red[0][i][tx] + red[1][i][tx] + red[2][i][tx] + red[3][i][tx]) *
                (1.0f / Cc);
      op[i] = v;
      mn = fminf(mn, v);
      mx = fmaxf(mx, v);
    }
    *reinterpret_cast<float4*>(e + (size_t)blockIdx.x * Ww + w0) = o;

    // Wave-level min/max reduce over the 64 lanes of ty==0.
#pragma unroll
    for (int off = 32; off > 0; off >>= 1) {
      mn = fminf(mn, __shfl_down(mn, off, 64));
      mx = fmaxf(mx, __shfl_down(mx, off, 64));
    }
    if (tx == 0) {
      atomicMin(&stats[b], fenc(mn));
      atomicMax(&stats[4 + b], fenc(mx));
    }
  }
}

// In-place normalize d_out. 65536 threads, 4 elements each (float4).
__global__ __launch_bounds__(256) void norm_kernel(float* __restrict__ e,
                                                   const unsigned int* __restrict__ stats) {
  const int t = blockIdx.x * 256 + threadIdx.x;           // 0..65535
  const int b = t >> 14;                                  // (t*4) >> 16
  const float mn = fdec(stats[b]);
  const float mx = fdec(stats[4 + b]);
  const float inv = 1.0f / fmaxf(mx - mn, 1e-6f);
  float4 v = reinterpret_cast<float4*>(e)[t];
  v.x = (v.x - mn) * inv;
  v.y = (v.y - mn) * inv;
  v.z = (v.z - mn) * inv;
  v.w = (v.w - mn) * inv;
  reinterpret_cast<float4*>(e)[t] = v;
}

extern "C" void kernel_launch(void* const* d_in, const int* in_sizes, int n_in,
                              void* d_out, int out_size, void* d_ws, size_t ws_size,
                              hipStream_t stream) {
  const float* x = (const float*)d_in[0];
  float* out = (float*)d_out;             // e, then normalized in place
  unsigned int* stats = (unsigned int*)d_ws;  // 8 uints

  // Init: min keys -> 0xFFFFFFFF, max keys -> 0.
  hipMemsetAsync(stats, 0xFF, 4 * sizeof(unsigned int), stream);
  hipMemsetAsync(stats + 4, 0x00, 4 * sizeof(unsigned int), stream);

  entropy_kernel<<<dim3(Bb * Hh), dim3(64, 4), 0, stream>>>(x, out, stats);
  norm_kernel<<<dim3((Bb * Hh * Ww / 4) / 256), dim3(256), 0, stream>>>(out, stats);
}